// Round 1
// baseline (523.064 us; speedup 1.0000x reference)
//
#include <hip/hip_runtime.h>
#include <cstdint>
#include <cstddef>

// Problem constants (from reference): B=32, S=1024, H=768, L=28, NH=8, HD=96
// d_out = [loss(1), logits(896)] f32.
// Workspace needed ~169 MiB (see offsets in kernel_launch).

using short8 = __attribute__((ext_vector_type(8))) short;   // 8 bf16 = 16B (guide-verified MFMA frag type)
using f32x4  = __attribute__((ext_vector_type(4))) float;

__device__ __forceinline__ short f2bf(float f) {   // f32 -> bf16 (RNE), bit-level, header-independent
  unsigned u = __builtin_bit_cast(unsigned, f);
  u = (u + 0x7fffu + ((u >> 16) & 1u)) >> 16;
  return (short)u;
}

#define MFMA16(a, b, c) __builtin_amdgcn_mfma_f32_16x16x32_bf16((a), (b), (c), 0, 0, 0)

__device__ __forceinline__ void gld16(const void* g, void* l) {
  // async global->LDS, 16B/lane; LDS dest is wave-uniform base + lane*16 (HW behavior)
  __builtin_amdgcn_global_load_lds((const __attribute__((address_space(1))) void*)g,
                                   (__attribute__((address_space(3))) void*)l, 16, 0, 0);
}

// ---------------------------------------------------------------------------
// elementwise f32 -> bf16 (hidden), 8 elems/thread, exact-size grid
__global__ __launch_bounds__(256) void cvt_k(const float* __restrict__ in, short* __restrict__ out) {
  size_t i = ((size_t)blockIdx.x * 256 + threadIdx.x) * 8;
  float4 a = *(const float4*)(in + i);
  float4 b = *(const float4*)(in + i + 4);
  short8 w;
  w[0]=f2bf(a.x); w[1]=f2bf(a.y); w[2]=f2bf(a.z); w[3]=f2bf(a.w);
  w[4]=f2bf(b.x); w[5]=f2bf(b.y); w[6]=f2bf(b.z); w[7]=f2bf(b.w);
  *(short8*)(out + i) = w;
}

// ---------------------------------------------------------------------------
// transpose + convert: in f32 [K][N] row-major -> out bf16 [N][K] row-major.
// grid = (N/64, K/64), 256 threads, 64x64 tile via LDS.
__global__ __launch_bounds__(256) void tcvt_k(const float* __restrict__ in, short* __restrict__ out,
                                              int K, int N) {
  __shared__ float t[64][65];
  const int tid = threadIdx.x;
  const int bx = blockIdx.x, by = blockIdx.y;
  const int cr = tid >> 4, cc = (tid & 15) * 4;
#pragma unroll
  for (int p = 0; p < 4; p++) {
    int k = by * 64 + p * 16 + cr;
    float4 v = *(const float4*)(in + (size_t)k * N + bx * 64 + cc);
    t[p*16+cr][cc]   = v.x; t[p*16+cr][cc+1] = v.y;
    t[p*16+cr][cc+2] = v.z; t[p*16+cr][cc+3] = v.w;
  }
  __syncthreads();
  const int nl = tid >> 2, kl0 = (tid & 3) * 16;
  short8 w0, w1;
#pragma unroll
  for (int j = 0; j < 8; j++) w0[j] = f2bf(t[kl0 + j][nl]);
#pragma unroll
  for (int j = 0; j < 8; j++) w1[j] = f2bf(t[kl0 + 8 + j][nl]);
  short* op = out + (size_t)(bx * 64 + nl) * K + by * 64 + kl0;
  *(short8*)op       = w0;
  *(short8*)(op + 8) = w1;
}

// ---------------------------------------------------------------------------
// span mean-pooling: label_hidden[b,l,:] = mean(hidden[b, start:start+len, :])
// grid = B*L = 896 blocks, 256 threads (3 h-elems each)
__global__ __launch_bounds__(256) void pool_k(const float* __restrict__ hidden, const int* __restrict__ lp,
                                              float* __restrict__ outf, short* __restrict__ outb) {
  const int blk = blockIdx.x;            // b*28 + l
  const int b = blk / 28;
  const int start = lp[blk * 2], len = lp[blk * 2 + 1];
  const float inv = 1.f / (float)max(len, 1);
#pragma unroll
  for (int j = 0; j < 3; j++) {
    int h = threadIdx.x + j * 256;
    float s = 0.f;
    for (int q = 0; q < len; q++)
      s += hidden[((size_t)b * 1024 + start + q) * 768 + h];
    float m = s * inv;
    outf[(size_t)blk * 768 + h] = m;
    outb[(size_t)blk * 768 + h] = f2bf(m);
  }
}

// ---------------------------------------------------------------------------
// 128x128 MFMA GEMM, A [M,K] bf16 row-major, Bt [N,K] bf16 row-major (B transposed).
// 256 threads = 4 waves (2x2), each wave 64x64 (4x4 frags of 16x16x32).
// LDS tiles [128 rows][32 k] with XOR swizzle (bits4-5 ^= bits7-8) -> 2-way conflicts (free).
// MODE 0: outb[r*N+c] = bf16(acc + bias[c])                       (Q proj)
// MODE 1: KV scatter: k -> [b,n,s,d] bf16, v -> [b,n,d,s] bf16    (KV proj)
// MODE 2: outf[r*N+c] = acc + bias[c]                             (Wo, FFN2)
// MODE 3: outb[r*N+c] = bf16(gelu_exact(acc + bias[c]))           (FFN1)
template <int MODE>
__global__ __launch_bounds__(256) void gemm_k(
    const short* __restrict__ A, const short* __restrict__ Bt,
    const float* __restrict__ bias, const float* __restrict__ bias2,
    float* __restrict__ outf, short* __restrict__ outb, short* __restrict__ outb2,
    int K, int N) {
  __shared__ __align__(16) char lds[16384];
  const int tid = threadIdx.x, lane = tid & 63, wid = tid >> 6;
  const int wm = wid >> 1, wn = wid & 1;
  const int m0 = blockIdx.x * 128, n0 = blockIdx.y * 128;
  const int lr = lane & 15, lg = lane >> 4;

  // fragment read offsets (swizzled); +i*1024 steps rows by 16 (XOR bits unchanged)
  int aoff = (wm * 64 + lr) * 64 + lg * 16;
  aoff ^= ((aoff >> 7) & 3) << 4;
  int boff = (wn * 64 + lr) * 64 + lg * 16;
  boff ^= ((boff >> 7) & 3) << 4;
  boff += 8192;

  // staging: LDS linear dest d -> logical offset o = swz(d) -> global (row, col)
  const int d0 = wid * 1024 + lane * 16;
  const int d1 = d0 + 4096;
  const int o0 = d0 ^ (((d0 >> 7) & 3) << 4);
  const int o1 = d1 ^ (((d1 >> 7) & 3) << 4);
  const int r0 = o0 >> 6, c0 = (o0 & 63) >> 1;
  const int r1 = o1 >> 6, c1 = (o1 & 63) >> 1;
  const short* pA0 = A + (size_t)(m0 + r0) * K + c0;
  const short* pA1 = A + (size_t)(m0 + r1) * K + c1;
  const short* pB0 = Bt + (size_t)(n0 + r0) * K + c0;
  const short* pB1 = Bt + (size_t)(n0 + r1) * K + c1;
  char* sA0 = lds + wid * 1024;
  char* sA1 = lds + 4096 + wid * 1024;
  char* sB0 = lds + 8192 + wid * 1024;
  char* sB1 = lds + 12288 + wid * 1024;

  f32x4 acc[4][4];
  const f32x4 zf = {0.f, 0.f, 0.f, 0.f};
#pragma unroll
  for (int i = 0; i < 4; i++)
#pragma unroll
    for (int j = 0; j < 4; j++) acc[i][j] = zf;

  for (int k0 = 0; k0 < K; k0 += 32) {
    __syncthreads();                       // previous iter's LDS reads done
    gld16(pA0 + k0, sA0);
    gld16(pA1 + k0, sA1);
    gld16(pB0 + k0, sB0);
    gld16(pB1 + k0, sB1);
    __syncthreads();                       // compiler drains vmcnt before barrier
    short8 af[4], bf[4];
#pragma unroll
    for (int i = 0; i < 4; i++) af[i] = *(const short8*)(lds + aoff + i * 1024);
#pragma unroll
    for (int j = 0; j < 4; j++) bf[j] = *(const short8*)(lds + boff + j * 1024);
#pragma unroll
    for (int i = 0; i < 4; i++)
#pragma unroll
      for (int j = 0; j < 4; j++)
        acc[i][j] = MFMA16(af[i], bf[j], acc[i][j]);
  }

  if constexpr (MODE == 1) {
    const int b = m0 >> 10;                  // 128 | 1024 -> b uniform per block
    const int sb = (m0 & 1023) + wm * 64;
#pragma unroll
    for (int j = 0; j < 4; j++) {
      int c = n0 + wn * 64 + j * 16 + lr;
      bool isv = c >= 768;                   // uniform per (block, wave)
      int c7 = isv ? c - 768 : c;
      int nh = c7 / 96;
      int dd = c7 - nh * 96;
      float bb = isv ? bias2[c7] : bias[c7];
      size_t base = isv ? ((size_t)((b * 8 + nh) * 96 + dd)) * 1024
                        : (size_t)(b * 8 + nh) * 98304 + dd;
      short* op = isv ? outb2 : outb;
#pragma unroll
      for (int i = 0; i < 4; i++) {
        int s0 = sb + i * 16 + lg * 4;
#pragma unroll
        for (int t = 0; t < 4; t++) {
          short v = f2bf(acc[i][j][t] + bb);
          if (isv) op[base + s0 + t] = v;                     // vT[b,n,d,s]
          else     op[base + (size_t)(s0 + t) * 96] = v;      // k[b,n,s,d]
        }
      }
    }
  } else {
    const int rb = m0 + wm * 64;
    const int cb = n0 + wn * 64;
#pragma unroll
    for (int j = 0; j < 4; j++) {
      int c = cb + j * 16 + lr;
      float bb = bias[c];
#pragma unroll
      for (int i = 0; i < 4; i++) {
        int r = rb + i * 16 + lg * 4;
#pragma unroll
        for (int t = 0; t < 4; t++) {
          float v = acc[i][j][t] + bb;
          if constexpr (MODE == 0) {
            outb[(size_t)(r + t) * N + c] = f2bf(v);
          } else if constexpr (MODE == 2) {
            outf[(size_t)(r + t) * N + c] = v;
          } else {
            float ge = v * 0.5f * (1.f + erff(v * 0.70710678118654752f));
            outb[(size_t)(r + t) * N + c] = f2bf(ge);
          }
        }
      }
    }
  }
}

// ---------------------------------------------------------------------------
// cross-attention, one block per (b, head): q [28,96] x k^T -> softmax -> @ v
// scores kept in LDS [32][1032] f32 (pad 8 -> 4-way-max conflicts on frag reads).
#define SROW 1032
__global__ __launch_bounds__(256, 1) void attn_k(
    const short* __restrict__ qb, const short* __restrict__ kb,
    const short* __restrict__ vtb, short* __restrict__ ctxb) {
  __shared__ __align__(16) float sc[32 * SROW];   // 132 KB
  __shared__ float rowsum[28];
  const int b = blockIdx.x >> 3, n = blockIdx.x & 7;
  const int tid = threadIdx.x, lane = tid & 63, wid = tid >> 6;
  const int lr = lane & 15, lg = lane >> 4;
  const float rs = 0.10206207261596575f;          // 1/sqrt(96)
  const f32x4 zf = {0.f, 0.f, 0.f, 0.f};
  const short8 z8 = {0, 0, 0, 0, 0, 0, 0, 0};

  // Q fragments (hoisted): aq[mtile][kk], rows >= 28 zeroed
  short8 aq[2][3];
#pragma unroll
  for (int mt = 0; mt < 2; mt++) {
    int row = mt * 16 + lr;
#pragma unroll
    for (int kk = 0; kk < 3; kk++)
      aq[mt][kk] = (row < 28)
          ? *(const short8*)(qb + (size_t)(b * 28 + row) * 768 + n * 96 + kk * 32 + lg * 8)
          : z8;
  }

  // phase 1: scores = q @ k^T / sqrt(96); wave w owns s-range [w*256, w*256+256)
  const short* kbase = kb + (size_t)(b * 8 + n) * 98304;
#pragma unroll 2
  for (int st = 0; st < 16; st++) {
    int s0 = wid * 256 + st * 16;
    f32x4 a0 = zf, a1 = zf;
#pragma unroll
    for (int kk = 0; kk < 3; kk++) {
      short8 bk8 = *(const short8*)(kbase + (size_t)(s0 + lr) * 96 + kk * 32 + lg * 8);
      a0 = MFMA16(aq[0][kk], bk8, a0);
      a1 = MFMA16(aq[1][kk], bk8, a1);
    }
#pragma unroll
    for (int t = 0; t < 4; t++) {
      sc[(lg * 4 + t) * SROW + s0 + lr]        = a0[t] * rs;
      sc[(16 + lg * 4 + t) * SROW + s0 + lr]   = a1[t] * rs;
    }
  }
  __syncthreads();

  // phase 2: softmax (unnormalized exp; divide by rowsum at the end). wave w rows [7w, 7w+7)
  for (int rr = 0; rr < 7; rr++) {
    int r = wid * 7 + rr;
    float* rp = sc + r * SROW;
    float v[16];
    float mx = -3.0e38f;
#pragma unroll
    for (int t = 0; t < 16; t++) { v[t] = rp[lane + t * 64]; mx = fmaxf(mx, v[t]); }
#pragma unroll
    for (int o = 32; o > 0; o >>= 1) mx = fmaxf(mx, __shfl_xor(mx, o));
    float sm = 0.f;
#pragma unroll
    for (int t = 0; t < 16; t++) { v[t] = __expf(v[t] - mx); sm += v[t]; }
#pragma unroll
    for (int o = 32; o > 0; o >>= 1) sm += __shfl_xor(sm, o);
#pragma unroll
    for (int t = 0; t < 16; t++) rp[lane + t * 64] = v[t];
    if (lane == 0) rowsum[r] = sm;
  }
  for (int idx = tid; idx < 4 * SROW; idx += 256) sc[28 * SROW + idx] = 0.f;  // zero pad rows
  __syncthreads();

  // phase 3: ctx partial = P(s-range) @ V(s-range); wave-split over s
  f32x4 acc[2][6];
#pragma unroll
  for (int mt = 0; mt < 2; mt++)
#pragma unroll
    for (int nt = 0; nt < 6; nt++) acc[mt][nt] = zf;
  const short* vbase = vtb + (size_t)(b * 8 + n) * 98304;
#pragma unroll 2
  for (int ks = 0; ks < 8; ks++) {
    int s0 = wid * 256 + ks * 32;
    short8 pa[2];
#pragma unroll
    for (int mt = 0; mt < 2; mt++) {
      const float* pp = sc + (mt * 16 + lr) * SROW + s0 + lg * 8;
      short8 w;
#pragma unroll
      for (int t = 0; t < 8; t++) w[t] = f2bf(pp[t]);
      pa[mt] = w;
    }
#pragma unroll
    for (int nt = 0; nt < 6; nt++) {
      short8 bv8 = *(const short8*)(vbase + (size_t)(nt * 16 + lr) * 1024 + s0 + lg * 8);
      acc[0][nt] = MFMA16(pa[0], bv8, acc[0][nt]);
      acc[1][nt] = MFMA16(pa[1], bv8, acc[1][nt]);
    }
  }
  __syncthreads();                         // done reading sc; reuse for partials
  float* part = sc + wid * 3072;           // [4][32][96]
#pragma unroll
  for (int mt = 0; mt < 2; mt++)
#pragma unroll
    for (int nt = 0; nt < 6; nt++)
#pragma unroll
      for (int t = 0; t < 4; t++)
        part[(mt * 16 + lg * 4 + t) * 96 + nt * 16 + lr] = acc[mt][nt][t];
  __syncthreads();
  for (int idx = tid; idx < 2688; idx += 256) {
    int l = idx / 96, d = idx - (idx / 96) * 96;
    float s = sc[idx] + sc[3072 + idx] + sc[6144 + idx] + sc[9216 + idx];
    ctxb[(size_t)(b * 28 + l) * 768 + n * 96 + d] = f2bf(s / rowsum[l]);
  }
}

// ---------------------------------------------------------------------------
__device__ __forceinline__ float blk_sum4(float v, float* red) {
  const int lane = threadIdx.x & 63, wid = threadIdx.x >> 6;
#pragma unroll
  for (int o = 32; o > 0; o >>= 1) v += __shfl_xor(v, o);
  __syncthreads();
  if (lane == 0) red[wid] = v;
  __syncthreads();
  return red[0] + red[1] + red[2] + red[3];
}

// LN1: x1 = LayerNorm(attn_out + label_hidden)*g+b ; writes f32 + bf16. grid=896 rows
__global__ __launch_bounds__(256) void ln1_k(const float* __restrict__ ao, const float* __restrict__ lh,
                                             const float* __restrict__ g, const float* __restrict__ bb,
                                             float* __restrict__ x1, short* __restrict__ x1b) {
  __shared__ float red[4];
  const int row = blockIdx.x, tid = threadIdx.x;
  const size_t base = (size_t)row * 768;
  float x[3], s1 = 0.f, s2 = 0.f;
#pragma unroll
  for (int j = 0; j < 3; j++) {
    int c = tid + j * 256;
    x[j] = ao[base + c] + lh[base + c];
    s1 += x[j]; s2 += x[j] * x[j];
  }
  s1 = blk_sum4(s1, red);
  s2 = blk_sum4(s2, red);
  float mu = s1 * (1.f / 768.f);
  float inv = rsqrtf(s2 * (1.f / 768.f) - mu * mu + 1e-5f);
#pragma unroll
  for (int j = 0; j < 3; j++) {
    int c = tid + j * 256;
    float y = (x[j] - mu) * inv * g[c] + bb[c];
    x1[base + c] = y;
    x1b[base + c] = f2bf(y);
  }
}

// LN2 + logits: logit[row] = LN(z+x1)*g+b . wc + bc -> d_out[1+row]. grid=896
__global__ __launch_bounds__(256) void ln2_k(const float* __restrict__ z, const float* __restrict__ x1,
                                             const float* __restrict__ g, const float* __restrict__ bb,
                                             const float* __restrict__ wc, const float* __restrict__ bc,
                                             float* __restrict__ dout) {
  __shared__ float red[4];
  const int row = blockIdx.x, tid = threadIdx.x;
  const size_t base = (size_t)row * 768;
  float x[3], s1 = 0.f, s2 = 0.f;
#pragma unroll
  for (int j = 0; j < 3; j++) {
    int c = tid + j * 256;
    x[j] = z[base + c] + x1[base + c];
    s1 += x[j]; s2 += x[j] * x[j];
  }
  s1 = blk_sum4(s1, red);
  s2 = blk_sum4(s2, red);
  float mu = s1 * (1.f / 768.f);
  float inv = rsqrtf(s2 * (1.f / 768.f) - mu * mu + 1e-5f);
  float dacc = 0.f;
#pragma unroll
  for (int j = 0; j < 3; j++) {
    int c = tid + j * 256;
    float y = (x[j] - mu) * inv * g[c] + bb[c];
    dacc += y * wc[c];
  }
  dacc = blk_sum4(dacc, red);
  if (tid == 0) dout[1 + row] = dacc + bc[0];
}

// pairwise corr term: sum over (i pos, j neg) of relu(l_j - l_i + 0.3). grid=28 x 1024thr
__global__ __launch_bounds__(1024) void corr_k(const float* __restrict__ dout,
                                               const float* __restrict__ labels, float* __restrict__ acc) {
  __shared__ float lg[896], lb[896];
  __shared__ float red[16];
  const int tid = threadIdx.x;
  if (tid < 896) { lg[tid] = dout[1 + tid]; lb[tid] = labels[tid]; }
  __syncthreads();
  const int i = blockIdx.x * 32 + (tid >> 5);
  float a = 0.f;
  if (lb[i] == 1.f) {
    float li = lg[i];
    int j0 = tid & 31;
#pragma unroll 4
    for (int k2 = 0; k2 < 28; k2++) {
      int j = j0 + k2 * 32;
      if (lb[j] == 0.f) a += fmaxf(lg[j] - li + 0.3f, 0.f);
    }
  }
#pragma unroll
  for (int o = 32; o > 0; o >>= 1) a += __shfl_xor(a, o);
  if ((tid & 63) == 0) red[tid >> 6] = a;
  __syncthreads();
  if (tid == 0) {
    float t = 0.f;
#pragma unroll
    for (int w = 0; w < 16; w++) t += red[w];
    atomicAdd(acc, t);
  }
}

// final: loss = 0.8*mean(bce) + 0.2*corr_sum/(pos*neg). single block.
__global__ __launch_bounds__(1024) void loss_k(const float* __restrict__ din, const float* __restrict__ labels,
                                               const float* __restrict__ acc, float* __restrict__ dout) {
  __shared__ float red[48];
  const int tid = threadIdx.x;
  float bce = 0.f, pos = 0.f, neg = 0.f;
  if (tid < 896) {
    float l = din[1 + tid], y = labels[tid];
    bce = fmaxf(l, 0.f) - l * y + log1pf(expf(-fabsf(l)));
    pos = y; neg = 1.f - y;
  }
#pragma unroll
  for (int o = 32; o > 0; o >>= 1) {
    bce += __shfl_xor(bce, o); pos += __shfl_xor(pos, o); neg += __shfl_xor(neg, o);
  }
  if ((tid & 63) == 0) { red[tid >> 6] = bce; red[16 + (tid >> 6)] = pos; red[32 + (tid >> 6)] = neg; }
  __syncthreads();
  if (tid == 0) {
    float sb = 0.f, sp = 0.f, sn = 0.f;
#pragma unroll
    for (int w = 0; w < 16; w++) { sb += red[w]; sp += red[16 + w]; sn += red[32 + w]; }
    float denom = sp * sn;
    float corr = denom > 0.f ? acc[0] / fmaxf(denom, 1.f) : 0.f;
    dout[0] = 0.8f * sb * (1.f / 896.f) + 0.2f * corr;
  }
}

// ---------------------------------------------------------------------------
extern "C" void kernel_launch(void* const* d_in, const int* in_sizes, int n_in,
                              void* d_out, int out_size, void* d_ws, size_t ws_size,
                              hipStream_t stream) {
  const float* hidden = (const float*)d_in[0];
  const float* labels = (const float*)d_in[1];
  const int*   lpos   = (const int*)d_in[2];
  const float* Wq = (const float*)d_in[3];  const float* bq = (const float*)d_in[4];
  const float* Wk = (const float*)d_in[5];  const float* bk = (const float*)d_in[6];
  const float* Wv = (const float*)d_in[7];  const float* bv = (const float*)d_in[8];
  const float* Wo = (const float*)d_in[9];  const float* bo = (const float*)d_in[10];
  const float* g_mha = (const float*)d_in[11]; const float* b_mha = (const float*)d_in[12];
  const float* W1 = (const float*)d_in[13]; const float* bf1 = (const float*)d_in[14];
  const float* W2 = (const float*)d_in[15]; const float* bf2 = (const float*)d_in[16];
  const float* g_ffn = (const float*)d_in[17]; const float* b_ffn = (const float*)d_in[18];
  const float* wc = (const float*)d_in[19]; const float* bc = (const float*)d_in[20];
  float* dout = (float*)d_out;

  char* ws = (char*)d_ws;
  size_t off = 0;
  auto alloc = [&](size_t bytes) { char* p = ws + off; off += (bytes + 255) & ~(size_t)255; return p; };
  short* hid_b = (short*)alloc(32ull * 1024 * 768 * 2);        // 50.3 MB
  short* WqT   = (short*)alloc(768ull * 768 * 2);
  short* WkvT  = (short*)alloc(1536ull * 768 * 2);
  short* WoT   = (short*)alloc(768ull * 768 * 2);
  short* W1T   = (short*)alloc(1536ull * 768 * 2);
  short* W2T   = (short*)alloc(768ull * 1536 * 2);
  float* poolf = (float*)alloc(896ull * 768 * 4);
  short* poolb = (short*)alloc(896ull * 768 * 2);
  short* qbf   = (short*)alloc(896ull * 768 * 2);
  short* kbf   = (short*)alloc(32ull * 8 * 1024 * 96 * 2);     // 50.3 MB [b,n,s,d]
  short* vtb   = (short*)alloc(32ull * 8 * 96 * 1024 * 2);     // 50.3 MB [b,n,d,s]
  short* ctxb  = (short*)alloc(896ull * 768 * 2);
  float* aout  = (float*)alloc(896ull * 768 * 4);
  float* x1    = (float*)alloc(896ull * 768 * 4);
  short* x1b   = (short*)alloc(896ull * 768 * 2);
  short* hb    = (short*)alloc(896ull * 1536 * 2);
  float* zbuf  = (float*)alloc(896ull * 768 * 4);
  float* cacc  = (float*)alloc(256);
  (void)in_sizes; (void)n_in; (void)out_size; (void)ws_size;

  hipMemsetAsync(cacc, 0, 4, stream);
  cvt_k<<<12288, 256, 0, stream>>>(hidden, hid_b);
  tcvt_k<<<dim3(12, 12), 256, 0, stream>>>(Wq, WqT, 768, 768);
  tcvt_k<<<dim3(12, 12), 256, 0, stream>>>(Wk, WkvT, 768, 768);
  tcvt_k<<<dim3(12, 12), 256, 0, stream>>>(Wv, WkvT + 768 * 768, 768, 768);
  tcvt_k<<<dim3(12, 12), 256, 0, stream>>>(Wo, WoT, 768, 768);
  tcvt_k<<<dim3(24, 12), 256, 0, stream>>>(W1, W1T, 768, 1536);
  tcvt_k<<<dim3(12, 24), 256, 0, stream>>>(W2, W2T, 1536, 768);
  pool_k<<<896, 256, 0, stream>>>(hidden, lpos, poolf, poolb);
  // q = label_hidden @ Wq + bq  -> bf16 [896,768]
  gemm_k<0><<<dim3(7, 6), 256, 0, stream>>>(poolb, WqT, bq, nullptr, nullptr, qbf, nullptr, 768, 768);
  // k,v = hidden @ [Wk|Wv] + b  -> scattered bf16
  gemm_k<1><<<dim3(256, 12), 256, 0, stream>>>(hid_b, WkvT, bk, bv, nullptr, kbf, vtb, 768, 1536);
  attn_k<<<256, 256, 0, stream>>>(qbf, kbf, vtb, ctxb);
  // attn_out = ctx @ Wo + bo -> f32
  gemm_k<2><<<dim3(7, 6), 256, 0, stream>>>(ctxb, WoT, bo, nullptr, aout, nullptr, nullptr, 768, 768);
  ln1_k<<<896, 256, 0, stream>>>(aout, poolf, g_mha, b_mha, x1, x1b);
  // h = gelu(x1 @ W1 + bf1) -> bf16 [896,1536]
  gemm_k<3><<<dim3(7, 12), 256, 0, stream>>>(x1b, W1T, bf1, nullptr, nullptr, hb, nullptr, 768, 1536);
  // z = h @ W2 + bf2 -> f32 [896,768]
  gemm_k<2><<<dim3(7, 6), 256, 0, stream>>>(hb, W2T, bf2, nullptr, zbuf, nullptr, nullptr, 1536, 768);
  ln2_k<<<896, 256, 0, stream>>>(zbuf, x1, g_ffn, b_ffn, wc, bc, dout);
  corr_k<<<28, 1024, 0, stream>>>(dout, labels, cacc);
  loss_k<<<1, 1024, 0, stream>>>(dout, labels, cacc, dout);
}